// Round 14
// baseline (823.541 us; speedup 1.0000x reference)
//
#include <hip/hip_runtime.h>
#include <hip/hip_bf16.h>
#include <stdint.h>
#include <stddef.h>

typedef __attribute__((ext_vector_type(8))) short short8;
typedef __attribute__((ext_vector_type(4))) float f32x4;
typedef __attribute__((ext_vector_type(16))) float f32x16;

#define NB 2048
#define HD 512
#define SD 256

#define AROW 516   // shorts per s-row (512 k + 4 pad): bank step 258%32=2 ->
                   // 2 lanes/bank on b128 reads/writes = free (m136)

__device__ __forceinline__ short f2bf(float x) {
  __hip_bfloat16 h = __float2bfloat16(x);
  return *reinterpret_cast<short*>(&h);
}

__device__ __forceinline__ float fast_tanh(float x) {
  x = fminf(fmaxf(x, -15.f), 15.f);
  float e = __expf(2.f * x);
  return __fdividef(e - 1.f, e + 1.f);
}

// ---- Wtb16[kb][j][kk] = bf16(W[kb*16+kk][j]), kb in [0,32) ----
__global__ __launch_bounds__(256) void wconv_kernel(const float* __restrict__ W,
                                                    short* __restrict__ Wtb16) {
  __shared__ float tile[32][33];
  const int bx = blockIdx.x;
  const int tk0 = (bx & 15) * 32;
  const int tj0 = (bx >> 4) * 32;
  const int lx = threadIdx.x & 31;
  const int ly = threadIdx.x >> 5;
  for (int r = 0; r < 4; ++r) {
    int yy = ly + r * 8;
    tile[yy][lx] = W[(size_t)(tk0 + yy) * HD + tj0 + lx];
  }
  __syncthreads();
  for (int r = 0; r < 4; ++r) {
    int yy = ly + r * 8;
    const int k = tk0 + lx;
    Wtb16[(size_t)(k >> 4) * (HD * 16) + (size_t)(tj0 + yy) * 16 + (k & 15)] =
        f2bf(tile[lx][yy]);
  }
}

// ---- alignment[n][s] = sum_j tanh( sum_k hs[n,k,s]*W[k,j] + b[j] ) * c[j] ----
// Block = 32 s x FULL 512 j, 256 threads = 4 waves (disjoint 128-j strips).
// LDS = one 32s x 512k bf16 A-panel (33 KB) -> FOUR independent blocks/CU:
// their phase-1 HBM bursts and phase-2 MFMA loops interleave structurally.
// Phase 1: per thread 2 batches of 32 back-to-back scalar loads (8 KB/wave in
// flight, no pack interleaved), then pack -> 4x ds_write_b128. One barrier.
// Phase 2: barrier-free full-unroll k-loop (32 x K16), W from L2 via 2-deep
// named reg-ring, A from LDS via 2-deep ring, refills issued after the MFMAs.
__global__ void __launch_bounds__(256, 4)
align_kernel(const float* __restrict__ hs, const short* __restrict__ Wtb16,
             const float* __restrict__ bias, const float* __restrict__ ctxv,
             float* __restrict__ align_out)
{
  __shared__ short As[32 * AROW];   // 33 KB
  __shared__ float abuf[32];

  const int tid = threadIdx.x;
  const int n = blockIdx.x >> 3;
  const int s0 = (blockIdx.x & 7) * 32;
  const float* hsn = hs + (size_t)n * (HD * SD) + s0;

  if (tid < 32) abuf[tid] = 0.f;

  // ---- phase 1: stage A-panel (32 s x 512 k bf16)
  // thread -> s = tid&31, k-range [kg*64, kg*64+64), two 32-load batches
  {
    const int a_s = tid & 31;
    const int kg = tid >> 5;              // 0..7
    const float* src0 = hsn + a_s + (size_t)(kg * 64) * SD;
    short* dst = &As[a_s * AROW + kg * 64];
    #pragma unroll
    for (int b = 0; b < 2; ++b) {
      float ra[32];
      #pragma unroll
      for (int e = 0; e < 32; ++e)
        ra[e] = src0[(size_t)(b * 32 + e) * SD];
      #pragma unroll
      for (int o = 0; o < 4; ++o) {
        short8 pk;
        #pragma unroll
        for (int e = 0; e < 8; ++e) pk[e] = f2bf(ra[o * 8 + e]);
        *(short8*)(dst + b * 32 + o * 8) = pk;
      }
    }
  }
  __syncthreads();

  // ---- phase 2: barrier-free MFMA loop
  const int lane = tid & 63;
  const int wid = tid >> 6;              // 0..3
  const int jb = wid * 128;              // wave j-strip
  const int l31 = lane & 31;
  const int hg = lane >> 5;              // k-half: k = hg*8 + e

  f32x16 acc[4];
  #pragma unroll
  for (int p = 0; p < 4; ++p)
    #pragma unroll
    for (int q = 0; q < 16; ++q) acc[p][q] = 0.f;

  // W fragment base: row j = jb + p*32 + l31, k-octet hg (p stride 32*16)
  const short* wlane = Wtb16 + (size_t)(jb + l31) * 16 + hg * 8;
  const int afo = l31 * AROW + hg * 8;   // + kb*16

  short8 wb[2][4];   // W ring, 2 deep x 4 j-tiles
  short8 ab[2];      // A ring, 2 deep

  #pragma unroll
  for (int d = 0; d < 2; ++d) {
    const short* wk = wlane + (size_t)d * (HD * 16);
    #pragma unroll
    for (int p = 0; p < 4; ++p)
      wb[d][p] = *(const short8*)(wk + p * (32 * 16));
    ab[d] = *(const short8*)&As[afo + d * 16];
  }

  #pragma unroll
  for (int kb = 0; kb < 32; ++kb) {
    const int rs = kb & 1;

    __builtin_amdgcn_s_setprio(1);
    acc[0] = __builtin_amdgcn_mfma_f32_32x32x16_bf16(wb[rs][0], ab[rs], acc[0], 0, 0, 0);
    acc[1] = __builtin_amdgcn_mfma_f32_32x32x16_bf16(wb[rs][1], ab[rs], acc[1], 0, 0, 0);
    acc[2] = __builtin_amdgcn_mfma_f32_32x32x16_bf16(wb[rs][2], ab[rs], acc[2], 0, 0, 0);
    acc[3] = __builtin_amdgcn_mfma_f32_32x32x16_bf16(wb[rs][3], ab[rs], acc[3], 0, 0, 0);
    __builtin_amdgcn_s_setprio(0);

    // refill just-consumed ring slots for kb+2 (issued after the MFMAs)
    if (kb < 30) {
      const short* wk = wlane + (size_t)(kb + 2) * (HD * 16);
      #pragma unroll
      for (int p = 0; p < 4; ++p)
        wb[rs][p] = *(const short8*)(wk + p * (32 * 16));
      ab[rs] = *(const short8*)&As[afo + (kb + 2) * 16];
    }
  }

  // ---- epilogue: D col = s = l31, row(q) = (q&3)+8*(q>>2)+4*hg (+p*32)
  float part = 0.f;
  #pragma unroll
  for (int p = 0; p < 4; ++p) {
    const int jfr = jb + p * 32 + hg * 4;
    #pragma unroll
    for (int g = 0; g < 4; ++g) {
      const int j4 = jfr + g * 8;
      f32x4 bv = *(const f32x4*)(bias + j4);
      f32x4 cv = *(const f32x4*)(ctxv + j4);
      #pragma unroll
      for (int r = 0; r < 4; ++r) {
        const int q = g * 4 + r;
        part += fast_tanh(acc[p][q] + bv[r]) * cv[r];
      }
    }
  }
  part += __shfl_xor(part, 32);          // combine hg halves (same s-col)
  if (lane < 32) atomicAdd(&abuf[l31], part);
  __syncthreads();
  if (tid < 32) align_out[(size_t)n * SD + s0 + tid] = abuf[tid];
}

// ---- softmax over s + context[n,h] = sum_s attn[s]*hs[n,h,s] ----
__global__ __launch_bounds__(256) void ctx_kernel(const float* __restrict__ hs,
                                                  const float* __restrict__ align_in,
                                                  float* __restrict__ out)
{
  __shared__ __align__(16) float attn_s[256];
  __shared__ float red[8];
  const int n = blockIdx.x;
  const int t = threadIdx.x;
  const int lane = t & 63, wid = t >> 6;

  float a = align_in[(size_t)n * 256 + t];
  float m = a;
  #pragma unroll
  for (int off = 32; off; off >>= 1) m = fmaxf(m, __shfl_xor(m, off));
  if (lane == 0) red[wid] = m;
  __syncthreads();
  m = fmaxf(fmaxf(red[0], red[1]), fmaxf(red[2], red[3]));
  float e = __expf(a - m);
  float s = e;
  #pragma unroll
  for (int off = 32; off; off >>= 1) s += __shfl_xor(s, off);
  if (lane == 0) red[4 + wid] = s;
  __syncthreads();
  s = red[4] + red[5] + red[6] + red[7];
  attn_s[t] = e / s;
  __syncthreads();

  const int grp = t & 7;      // s-chunk of 32
  const int hrow = t >> 3;    // 0..31
  float av[32];
  #pragma unroll
  for (int u = 0; u < 8; ++u) {
    float4 v = *(const float4*)&attn_s[grp * 32 + u * 4];
    av[4*u+0] = v.x; av[4*u+1] = v.y; av[4*u+2] = v.z; av[4*u+3] = v.w;
  }
  const float* hb = hs + (size_t)n * (HD * SD) + grp * 32;
  for (int it = 0; it < 16; ++it) {
    const int h = it * 32 + hrow;
    const float4* p = (const float4*)(hb + (size_t)h * SD);
    float acc = 0.f;
    #pragma unroll
    for (int u = 0; u < 8; ++u) {
      float4 v = p[u];
      acc += av[4*u+0]*v.x + av[4*u+1]*v.y + av[4*u+2]*v.z + av[4*u+3]*v.w;
    }
    acc += __shfl_xor(acc, 1);
    acc += __shfl_xor(acc, 2);
    acc += __shfl_xor(acc, 4);
    if (grp == 0) out[(size_t)n * HD + h] = acc;
  }
}

extern "C" void kernel_launch(void* const* d_in, const int* in_sizes, int n_in,
                              void* d_out, int out_size, void* d_ws, size_t ws_size,
                              hipStream_t stream) {
  (void)in_sizes; (void)n_in; (void)out_size; (void)ws_size;
  const float* hs = (const float*)d_in[0];
  const float* W  = (const float*)d_in[1];
  const float* b  = (const float*)d_in[2];
  const float* c  = (const float*)d_in[3];
  float* out = (float*)d_out;

  float* align_ws = (float*)d_ws;                                  // 2 MB
  short* Wtb16 = (short*)((char*)d_ws + (size_t)NB * SD * 4);      // 512 KB

  wconv_kernel<<<256, 256, 0, stream>>>(W, Wtb16);
  align_kernel<<<NB * 8, 256, 0, stream>>>(hs, Wtb16, b, c, align_ws);
  ctx_kernel<<<NB, 256, 0, stream>>>(hs, align_ws, out);
}